// Round 15
// baseline (4656.331 us; speedup 1.0000x reference)
//
#include <hip/hip_runtime.h>

// LSTM decoder B=64,S=512,D=512,H=512,L=2 — Round 15: R11 + per-wave subflags.
// Identical to R11 (best: 2020us) EXCEPT the exchange handshake:
//   - each cell wave (w=0..3) posts its OWN subflag after draining its own
//     h stores (s_waitcnt vmcnt(0)) — no block-wide drain rendezvous
//   - consumers: ALL 8 waves poll; one dwordx4/lane = one producer block's 4
//     subflags (min4 + ballot) — same poll traffic as R11's single dword
//   - barriers per iter: 3 -> 2 (staging, Gp); no post-poll barrier
// Compute path unchanged: K-split 8 waves, weights pinned in 64 VGPRs.

#define NB 64
#define NS 512
#define ND 512
#define NH 512

typedef __attribute__((ext_vector_type(8))) short short8;
typedef __attribute__((ext_vector_type(4))) float f32x4;
typedef __attribute__((ext_vector_type(4))) unsigned int u32x4;
typedef unsigned long long ull;

// ---- ws layout (bytes) ----
#define WPK_OFF   0                 // 8,388,608
#define H0_OFF    8388608           // 4 bufs * 65536
#define H1_OFF    8650752           // 2 bufs * 65536
#define FLAGS_OFF 8781824           // 1024 u32 (4 grp x 2 role x 32 us x 4 w)
#define WPK_ELEMS_PER_ROLE (128 * 32 * 512)

__device__ __forceinline__ unsigned int pack2bf(float a, float b) {
    unsigned int ua = __builtin_bit_cast(unsigned int, a);
    unsigned int ub = __builtin_bit_cast(unsigned int, b);
    ua += 0x7fffu + ((ua >> 16) & 1u);   // RNE
    ub += 0x7fffu + ((ub >> 16) & 1u);
    return (ua >> 16) | (ub & 0xffff0000u);
}
__device__ __forceinline__ unsigned short bf16r(float a) {
    unsigned int ua = __builtin_bit_cast(unsigned int, a);
    ua += 0x7fffu + ((ua >> 16) & 1u);
    return (unsigned short)(ua >> 16);
}

// L3-coherent primitives (relaxed agent atomics -> sc1, no cache maintenance)
__device__ __forceinline__ ull ld_h64(const void* p) {
    return __hip_atomic_load((const ull*)p, __ATOMIC_RELAXED, __HIP_MEMORY_SCOPE_AGENT);
}
__device__ __forceinline__ void st_h32(void* p, unsigned int v) {
    __hip_atomic_store((unsigned int*)p, v, __ATOMIC_RELAXED, __HIP_MEMORY_SCOPE_AGENT);
}
__device__ __forceinline__ void st_flag(unsigned int* p, unsigned int v) {
    __hip_atomic_store(p, v, __ATOMIC_RELAXED, __HIP_MEMORY_SCOPE_AGENT);
}
// 4 subflags (one producer block), L3-coherent, one waitcnt
__device__ __forceinline__ u32x4 ld_flags4(const unsigned int* p) {
    u32x4 r;
    asm volatile("global_load_dwordx4 %0, %1, off sc0 sc1\n\ts_waitcnt vmcnt(0)"
                 : "=&v"(r) : "v"(p) : "memory");
    return r;
}

// Repack weights into MFMA B-fragment order:
// fragment (r, nt, k0i), lane l, elem j: B[k][n], n = nt*16+(l&15), k = k0i*32+(l>>4)*8+j
__global__ void prep_weights_k(const float* __restrict__ W_ih,
                               const float* __restrict__ W_hh,
                               unsigned int* __restrict__ wpk_u32) {
    long long gid = (long long)blockIdx.x * blockDim.x + threadIdx.x; // 524288
    int l   = (int)(gid & 63);
    int k0i = (int)((gid >> 6) & 31);
    int nt  = (int)((gid >> 11) & 127);
    int r   = (int)(gid >> 18);
    int n = nt * 16 + (l & 15);
    int k = k0i * 32 + ((l >> 4) << 3);
    const float* src;
    if (k < 512) src = W_ih + ((long long)r * 2048 + n) * 512 + k;
    else         src = W_hh + ((long long)r * 2048 + n) * 512 + (k - 512);
    uint4 v;
    v.x = pack2bf(src[0], src[1]);
    v.y = pack2bf(src[2], src[3]);
    v.z = pack2bf(src[4], src[5]);
    v.w = pack2bf(src[6], src[7]);
    ((uint4*)wpk_u32)[gid] = v;
}

__global__ void prep_state_k(const float* __restrict__ eh,
                             unsigned short* __restrict__ h0base,
                             unsigned short* __restrict__ h1base,
                             unsigned int* __restrict__ flags) {
    int i = blockIdx.x * blockDim.x + threadIdx.x;  // 32768
    if (i < NB * NH) {
        unsigned short hb = bf16r(eh[i]);
        (h0base + 3 * 32768)[i] = hb;   // h0_{-1} -> buf (-1)&3 = 3
        (h1base + 1 * 32768)[i] = hb;   // h1_{-1} -> buf (-1)&1 = 1
    }
    if (i < 1024) flags[i] = 0;
}

__global__ __launch_bounds__(512, 1)
void lstm_persist_k(const float* __restrict__ input,
                    const float* __restrict__ enc_c,
                    const float* __restrict__ b_ih,
                    const float* __restrict__ b_hh,
                    const unsigned short* __restrict__ wpk,
                    unsigned short* __restrict__ h0base,
                    unsigned short* __restrict__ h1base,
                    float* __restrict__ out,
                    unsigned int* __restrict__ flags) {
    __shared__ alignas(16) unsigned char smem[32768];   // A tile (fragment-packed)
    __shared__ float Gp[8][16][17];                     // partial gates per wave
    const int bid  = blockIdx.x;
    const int role = bid >> 7;             // 0: layer0(i), 1: layer1(i-1)
    const int lb   = bid & 127;
    const int ms   = lb >> 5;              // batch group 0..3 (sync group)
    const int us   = lb & 31;              // unit block 0..31
    const int m0   = ms << 4;
    const int tid  = threadIdx.x;
    const int lane = tid & 63;
    const int w    = tid >> 6;             // wave 0..7
    const int g    = __builtin_amdgcn_readfirstlane(w & 3);   // gate
    const int kh   = __builtin_amdgcn_readfirstlane(w >> 2);  // K-half

    const unsigned short* wp = wpk + (long long)role * WPK_ELEMS_PER_ROLE
                             + (long long)(g * 32 + us) * (32 * 512)
                             + (long long)kh * 16 * 512;
    const unsigned char* aBase = smem + kh * 16384;

    // ---- pin this wave's 16 B-fragments in registers (once) ----
    short8 wreg[16];
    #pragma unroll
    for (int j = 0; j < 16; ++j)
        wreg[j] = *(const short8*)(wp + j * 512 + lane * 8);
    #pragma unroll
    for (int j = 0; j < 16; ++j)
        asm volatile("" : "+v"(wreg[j]));

    // flags: fb[role*128 + us*4 + w]; lane's poll target = block lane's 4 subflags
    unsigned int* fb = flags + (ms << 8);
    unsigned int* myflagw = fb + (role << 7) + (us << 2) + w;   // valid for w<4
    const unsigned int* pollp = fb + (lane << 2);

    // ---- cell state + biases (threads 0..255 own the 256 cells) ----
    const int m_l = (tid >> 4) & 15, u_l = tid & 15;
    const int bcell = m0 + m_l;
    const int ucell = us * 16 + u_l;
    float cReg = 0.f, bias_i = 0.f, bias_f = 0.f, bias_g = 0.f, bias_o = 0.f;
    if (tid < 256) {
        cReg = enc_c[bcell * NH + ucell];
        const long long br = (long long)role * 2048;
        bias_i = b_ih[br + 0 * 512 + ucell] + b_hh[br + 0 * 512 + ucell];
        bias_f = b_ih[br + 1 * 512 + ucell] + b_hh[br + 1 * 512 + ucell];
        bias_g = b_ih[br + 2 * 512 + ucell] + b_hh[br + 2 * 512 + ucell];
        bias_o = b_ih[br + 3 * 512 + ucell] + b_hh[br + 3 * 512 + ucell];
    }

    // staging: thread handles 4 slots: {tid, 512+tid} = x-part, {1024+tid, 1536+tid} = h-part
    const int srow  = tid & 15;
    const int skoff = ((tid >> 4) & 3) << 3;

    // ---- role0: prefetch x(0) into registers ----
    float4 xp[4];
    if (role == 0) {
        #pragma unroll
        for (int j2 = 0; j2 < 2; ++j2) {
            int sid = j2 * 512 + tid;
            int k = (sid >> 6) * 32 + skoff;
            const float* s = input + (long long)(m0 + srow) * (NS * ND) + k;
            xp[2 * j2]     = *(const float4*)s;
            xp[2 * j2 + 1] = *(const float4*)(s + 4);
        }
    }

    for (int i = 0; i <= NS; ++i) {
        const bool active = (role == 0) ? (i < NS) : (i >= 1);

        if (active) {
            // ---- A: role0 pre-poll x staging (regs -> LDS x-region) ----
            if (role == 0) {
                #pragma unroll
                for (int j2 = 0; j2 < 2; ++j2) {
                    int sid = j2 * 512 + tid;
                    float4 lo = xp[2 * j2], hi = xp[2 * j2 + 1];
                    uint4 val;
                    val.x = pack2bf(lo.x, lo.y);
                    val.y = pack2bf(lo.z, lo.w);
                    val.z = pack2bf(hi.x, hi.y);
                    val.w = pack2bf(hi.z, hi.w);
                    *(uint4*)(smem + sid * 16) = val;
                }
            }

            // ---- B: poll (ALL waves; min over each block's 4 subflags) ----
            if (i > 0) {
                unsigned int thr;
                if (role == 0)
                    thr = (lane < 32) ? (unsigned int)i
                                      : (unsigned int)(i >= 2 ? i - 2 : 0);
                else
                    thr = (unsigned int)i;
                for (;;) {
                    u32x4 f = ld_flags4(pollp);
                    unsigned int mn  = f.x < f.y ? f.x : f.y;
                    unsigned int mn2 = f.z < f.w ? f.z : f.w;
                    mn = mn < mn2 ? mn : mn2;
                    if (__ballot(mn >= thr) == 0xFFFFFFFFFFFFFFFFULL) break;
                    __builtin_amdgcn_s_sleep(1);
                }
            }

            const unsigned short* h0prev = h0base + (((i - 1) & 3) << 15); // h0_{i-1}
            const unsigned short* hp = (role == 0) ? h0prev
                                     : h1base + ((i & 1) << 15);          // h1_{i-2}

            // ---- C: stage remaining A-parts ----
            if (role == 1) {
                // x-part = h0_{i-1} (slots tid, 512+tid)
                #pragma unroll
                for (int j2 = 0; j2 < 2; ++j2) {
                    int sid = j2 * 512 + tid;
                    int k = (sid >> 6) * 32 + skoff;
                    const ull* p = (const ull*)(h0prev + (long long)(m0 + srow) * 512 + k);
                    ull lo = ld_h64(p);
                    ull hi = ld_h64(p + 1);
                    uint4 val;
                    val.x = (unsigned int)lo; val.y = (unsigned int)(lo >> 32);
                    val.z = (unsigned int)hi; val.w = (unsigned int)(hi >> 32);
                    *(uint4*)(smem + sid * 16) = val;
                }
            }
            // h-part (both roles; slots 1024+tid, 1536+tid)
            #pragma unroll
            for (int j2 = 2; j2 < 4; ++j2) {
                int sid = j2 * 512 + tid;
                int k = ((sid >> 6) - 16) * 32 + skoff;
                const ull* p = (const ull*)(hp + (long long)(m0 + srow) * 512 + k);
                ull lo = ld_h64(p);
                ull hi = ld_h64(p + 1);
                uint4 val;
                val.x = (unsigned int)lo; val.y = (unsigned int)(lo >> 32);
                val.z = (unsigned int)hi; val.w = (unsigned int)(hi >> 32);
                *(uint4*)(smem + sid * 16) = val;
            }
            __syncthreads();   // barrier 1: A staged

            // ---- GEMM: wave (g,kh) -> 16 MFMAs, B from registers ----
            f32x4 acc0 = {0.f,0.f,0.f,0.f}, acc1 = {0.f,0.f,0.f,0.f};
            #pragma unroll
            for (int j = 0; j < 16; j += 2) {
                short8 a0 = *(const short8*)(aBase + (j + 0) * 1024 + lane * 16);
                short8 a1 = *(const short8*)(aBase + (j + 1) * 1024 + lane * 16);
                acc0 = __builtin_amdgcn_mfma_f32_16x16x32_bf16(a0, wreg[j + 0], acc0, 0, 0, 0);
                acc1 = __builtin_amdgcn_mfma_f32_16x16x32_bf16(a1, wreg[j + 1], acc1, 0, 0, 0);
            }
            f32x4 accS = acc0 + acc1;
            {
                int u_g  = lane & 15;
                int mrow = (lane >> 4) * 4;
                #pragma unroll
                for (int r = 0; r < 4; ++r)
                    Gp[w][mrow + r][u_g] = accS[r];
            }
            __syncthreads();   // barrier 2: Gp ready (GEMM reads of A done)

            if (tid < 256) {
                // ---- fused LSTM cell: sum two K-half partials ----
                float s0 = Gp[0][m_l][u_l] + Gp[4][m_l][u_l] + bias_i;
                float s1 = Gp[1][m_l][u_l] + Gp[5][m_l][u_l] + bias_f;
                float s2 = Gp[2][m_l][u_l] + Gp[6][m_l][u_l] + bias_g;
                float s3 = Gp[3][m_l][u_l] + Gp[7][m_l][u_l] + bias_o;
                float ii = 1.f / (1.f + expf(-s0));
                float ff = 1.f / (1.f + expf(-s1));
                float gv = tanhf(s2);
                float oo = 1.f / (1.f + expf(-s3));
                cReg = ff * cReg + ii * gv;
                float hn = oo * tanhf(cReg);

                // publish h (packed bf16 pair, sc1)
                float hn_p = __shfl_xor(hn, 1);
                if ((u_l & 1) == 0) {
                    unsigned int pk = pack2bf(hn, hn_p);
                    unsigned short* hbuf = (role == 0)
                        ? h0base + ((i & 3) << 15)             // h0_i
                        : h1base + (((i - 1) & 1) << 15);      // h1_{i-1}
                    st_h32((unsigned int*)hbuf + ((bcell * NH + ucell) >> 1), pk);
                }
                // per-wave drain -> this wave's rows visible at L3 -> subflag
                __builtin_amdgcn_sched_barrier(0);
                asm volatile("s_waitcnt vmcnt(0)" ::: "memory");
                __builtin_amdgcn_sched_barrier(0);
                if (lane == 0) st_flag(myflagw, (unsigned int)(i + 1));

                // off-handshake work AFTER the flag
                if (role == 1) {
                    int s = i - 1;
                    out[(long long)bcell * (NS * NH) + (long long)s * NH + ucell] = hn;
                    if (i == NS) {
                        float* dst = out + (long long)NB * NS * NH;
                        dst[bcell * NH + ucell] = hn;
                        dst[NB * NH + bcell * NH + ucell] = cReg;
                    }
                }
                if (role == 0 && i + 1 < NS) {
                    #pragma unroll
                    for (int j2 = 0; j2 < 2; ++j2) {
                        int sid = j2 * 512 + tid;
                        int k = (sid >> 6) * 32 + skoff;
                        const float* s = input + (long long)(m0 + srow) * (NS * ND)
                                               + (long long)(i + 1) * ND + k;
                        xp[2 * j2]     = *(const float4*)s;
                        xp[2 * j2 + 1] = *(const float4*)(s + 4);
                    }
                }
            } else {
                // waves 4-7: prefetch next x right away
                if (role == 0 && i + 1 < NS) {
                    #pragma unroll
                    for (int j2 = 0; j2 < 2; ++j2) {
                        int sid = j2 * 512 + tid;
                        int k = (sid >> 6) * 32 + skoff;
                        const float* s = input + (long long)(m0 + srow) * (NS * ND)
                                               + (long long)(i + 1) * ND + k;
                        xp[2 * j2]     = *(const float4*)s;
                        xp[2 * j2 + 1] = *(const float4*)(s + 4);
                    }
                }
            }
        } else {
            // inactive iter: still advance subflags (liveness for peers' polls)
            if (tid < 256 && lane == 0) st_flag(myflagw, (unsigned int)(i + 1));
        }
    }
}

extern "C" void kernel_launch(void* const* d_in, const int* in_sizes, int n_in,
                              void* d_out, int out_size, void* d_ws, size_t ws_size,
                              hipStream_t stream) {
    const float* input = (const float*)d_in[0];
    const float* enc_h = (const float*)d_in[1];
    const float* enc_c = (const float*)d_in[2];
    const float* W_ih  = (const float*)d_in[3];
    const float* W_hh  = (const float*)d_in[4];
    const float* b_ih  = (const float*)d_in[5];
    const float* b_hh  = (const float*)d_in[6];
    float* out = (float*)d_out;
    unsigned char* ws = (unsigned char*)d_ws;

    unsigned short* wpk    = (unsigned short*)(ws + WPK_OFF);
    unsigned short* h0base = (unsigned short*)(ws + H0_OFF);
    unsigned short* h1base = (unsigned short*)(ws + H1_OFF);
    unsigned int*   flags  = (unsigned int*)(ws + FLAGS_OFF);

    prep_weights_k<<<2048, 256, 0, stream>>>(W_ih, W_hh, (unsigned int*)wpk);
    prep_state_k<<<128, 256, 0, stream>>>(enc_h, h0base, h1base, flags);
    lstm_persist_k<<<256, 512, 0, stream>>>(input, enc_c, b_ih, b_hh, wpk,
                                            h0base, h1base, out, flags);
}

// Round 16
// 2160.796 us; speedup vs baseline: 2.1549x; 2.1549x over previous
//
#include <hip/hip_runtime.h>

// LSTM decoder B=64,S=512,D=512,H=512,L=2 — Round 16: R11 dual-rail.
// Block decode (perf-only assumption, R14-verified): xcd=bid&7 -> ms=xcd>>1,
// role=xcd&1, us=bid>>3 — each (group,role) on one XCD.
// GLOBAL rail: exactly R11 (sc1 h bufs + flags, same thresholds). LOCAL rail:
// mirror h bufs + flags via plain stores (producer L2) polled/read with sc0 —
// valid only when producer/consumer share an XCD; per-lane local-first poll
// with global fallback; staging slots select source by winning rail.
// D-phase split: local store -> sync -> LOCAL flag (fast ~200ns drain); then
// sc1 mirror + out -> sync -> GLOBAL flag (R11 semantics, consumed cross-XCD).

#define NB 64
#define NS 512
#define ND 512
#define NH 512

typedef __attribute__((ext_vector_type(8))) short short8;
typedef __attribute__((ext_vector_type(4))) float f32x4;
typedef __attribute__((ext_vector_type(4))) unsigned int u32x4;
typedef unsigned long long ull;

// ---- ws layout (bytes) ----
#define WPK_OFF   0                 // 8,388,608
#define H0G_OFF   8388608           // 4 bufs * 65536
#define H1G_OFF   8650752           // 2 bufs * 65536
#define H0L_OFF   8781824           // 4 bufs * 65536 (local mirror)
#define H1L_OFF   9043968           // 2 bufs * 65536 (local mirror)
#define GFL_OFF   9175040           // 256 u32
#define LFL_OFF   9176064           // 256 u32
#define WPK_ELEMS_PER_ROLE (128 * 32 * 512)

__device__ __forceinline__ unsigned int pack2bf(float a, float b) {
    unsigned int ua = __builtin_bit_cast(unsigned int, a);
    unsigned int ub = __builtin_bit_cast(unsigned int, b);
    ua += 0x7fffu + ((ua >> 16) & 1u);   // RNE
    ub += 0x7fffu + ((ub >> 16) & 1u);
    return (ua >> 16) | (ub & 0xffff0000u);
}
__device__ __forceinline__ unsigned short bf16r(float a) {
    unsigned int ua = __builtin_bit_cast(unsigned int, a);
    ua += 0x7fffu + ((ua >> 16) & 1u);
    return (unsigned short)(ua >> 16);
}

// GLOBAL rail primitives (relaxed agent atomics -> sc1)
__device__ __forceinline__ ull ld_h64(const void* p) {
    return __hip_atomic_load((const ull*)p, __ATOMIC_RELAXED, __HIP_MEMORY_SCOPE_AGENT);
}
__device__ __forceinline__ void st_h32(void* p, unsigned int v) {
    __hip_atomic_store((unsigned int*)p, v, __ATOMIC_RELAXED, __HIP_MEMORY_SCOPE_AGENT);
}
__device__ __forceinline__ unsigned int ld_flag(const unsigned int* p) {
    return __hip_atomic_load(p, __ATOMIC_RELAXED, __HIP_MEMORY_SCOPE_AGENT);
}
__device__ __forceinline__ void st_flag(unsigned int* p, unsigned int v) {
    __hip_atomic_store(p, v, __ATOMIC_RELAXED, __HIP_MEMORY_SCOPE_AGENT);
}
// LOCAL rail primitives (sc0: L1-bypass, L2 access)
__device__ __forceinline__ unsigned int ld_flag_sc0(const unsigned int* p) {
    unsigned int r;
    asm volatile("global_load_dword %0, %1, off sc0\n\ts_waitcnt vmcnt(0)"
                 : "=&v"(r) : "v"(p) : "memory");
    return r;
}
__device__ __forceinline__ u32x4 ld16_sc0(const void* p) {
    u32x4 r;
    asm volatile("global_load_dwordx4 %0, %1, off sc0\n\ts_waitcnt vmcnt(0)"
                 : "=&v"(r) : "v"(p) : "memory");
    return r;
}

// Repack weights into MFMA B-fragment order:
// fragment (r, nt, k0i), lane l, elem j: B[k][n], n = nt*16+(l&15), k = k0i*32+(l>>4)*8+j
__global__ void prep_weights_k(const float* __restrict__ W_ih,
                               const float* __restrict__ W_hh,
                               unsigned int* __restrict__ wpk_u32) {
    long long gid = (long long)blockIdx.x * blockDim.x + threadIdx.x; // 524288
    int l   = (int)(gid & 63);
    int k0i = (int)((gid >> 6) & 31);
    int nt  = (int)((gid >> 11) & 127);
    int r   = (int)(gid >> 18);
    int n = nt * 16 + (l & 15);
    int k = k0i * 32 + ((l >> 4) << 3);
    const float* src;
    if (k < 512) src = W_ih + ((long long)r * 2048 + n) * 512 + k;
    else         src = W_hh + ((long long)r * 2048 + n) * 512 + (k - 512);
    uint4 v;
    v.x = pack2bf(src[0], src[1]);
    v.y = pack2bf(src[2], src[3]);
    v.z = pack2bf(src[4], src[5]);
    v.w = pack2bf(src[6], src[7]);
    ((uint4*)wpk_u32)[gid] = v;
}

__global__ void prep_state_k(const float* __restrict__ eh,
                             unsigned short* __restrict__ h0g,
                             unsigned short* __restrict__ h1g,
                             unsigned short* __restrict__ h0l,
                             unsigned short* __restrict__ h1l,
                             unsigned int* __restrict__ gfl,
                             unsigned int* __restrict__ lfl) {
    int i = blockIdx.x * blockDim.x + threadIdx.x;  // 32768
    if (i < NB * NH) {
        unsigned short hb = bf16r(eh[i]);
        (h0g + 3 * 32768)[i] = hb;   // h0_{-1} -> buf 3
        (h1g + 1 * 32768)[i] = hb;   // h1_{-1} -> buf 1
        (h0l + 3 * 32768)[i] = hb;
        (h1l + 1 * 32768)[i] = hb;
    }
    if (i < 256) { gfl[i] = 0; lfl[i] = 0; }
}

__global__ __launch_bounds__(512, 1)
void lstm_persist_k(const float* __restrict__ input,
                    const float* __restrict__ enc_c,
                    const float* __restrict__ b_ih,
                    const float* __restrict__ b_hh,
                    const unsigned short* __restrict__ wpk,
                    unsigned short* __restrict__ h0g,
                    unsigned short* __restrict__ h1g,
                    unsigned short* __restrict__ h0l,
                    unsigned short* __restrict__ h1l,
                    float* __restrict__ out,
                    unsigned int* __restrict__ gfl,
                    unsigned int* __restrict__ lfl) {
    __shared__ alignas(16) unsigned char smem[32768];   // A tile (fragment-packed)
    __shared__ float Gp[8][16][17];                     // partial gates per wave
    const int bid  = blockIdx.x;
    const int xcd  = bid & 7;
    const int ms   = xcd >> 1;             // batch group 0..3
    const int role = xcd & 1;              // 0: layer0(i), 1: layer1(i-1)
    const int us   = bid >> 3;             // unit block 0..31
    const int m0   = ms << 4;
    const int tid  = threadIdx.x;
    const int lane = tid & 63;
    const int w    = tid >> 6;             // wave 0..7
    const int g    = __builtin_amdgcn_readfirstlane(w & 3);   // gate
    const int kh   = __builtin_amdgcn_readfirstlane(w >> 2);  // K-half

    const unsigned short* wp = wpk + (long long)role * WPK_ELEMS_PER_ROLE
                             + (long long)(g * 32 + us) * (32 * 512)
                             + (long long)kh * 16 * 512;
    const unsigned char* aBase = smem + kh * 16384;

    // ---- pin this wave's 16 B-fragments in registers (once) ----
    short8 wreg[16];
    #pragma unroll
    for (int j = 0; j < 16; ++j)
        wreg[j] = *(const short8*)(wp + j * 512 + lane * 8);
    #pragma unroll
    for (int j = 0; j < 16; ++j)
        asm volatile("" : "+v"(wreg[j]));

    unsigned int* gfb = gfl + (ms << 6);
    unsigned int* lfb = lfl + (ms << 6);
    unsigned int* mygf = gfb + (role << 5) + us;
    unsigned int* mylf = lfb + (role << 5) + us;

    // ---- cell state + biases (threads 0..255 own the 256 cells) ----
    const int m_l = (tid >> 4) & 15, u_l = tid & 15;
    const int bcell = m0 + m_l;
    const int ucell = us * 16 + u_l;
    float cReg = 0.f, bias_i = 0.f, bias_f = 0.f, bias_g = 0.f, bias_o = 0.f;
    if (tid < 256) {
        cReg = enc_c[bcell * NH + ucell];
        const long long br = (long long)role * 2048;
        bias_i = b_ih[br + 0 * 512 + ucell] + b_hh[br + 0 * 512 + ucell];
        bias_f = b_ih[br + 1 * 512 + ucell] + b_hh[br + 1 * 512 + ucell];
        bias_g = b_ih[br + 2 * 512 + ucell] + b_hh[br + 2 * 512 + ucell];
        bias_o = b_ih[br + 3 * 512 + ucell] + b_hh[br + 3 * 512 + ucell];
    }

    // staging: slots {tid,512+tid}=x-part, {1024+tid,1536+tid}=h-part
    const int srow  = tid & 15;
    const int skoff = ((tid >> 4) & 3) << 3;
    // h-part producer indices in poll-lane space (own-role half)
    const int pown = ((w * 32 + skoff) >> 4);            // 0..15
    const int pl1  = pown + (role ? 32 : 0);             // slot j2=2
    const int pl2  = pl1 + 16;                           // slot j2=3

    // ---- role0: prefetch x(0) into registers ----
    float4 xp[4];
    if (role == 0) {
        #pragma unroll
        for (int j2 = 0; j2 < 2; ++j2) {
            int sid = j2 * 512 + tid;
            int k = (sid >> 6) * 32 + skoff;
            const float* s = input + (long long)(m0 + srow) * (NS * ND) + k;
            xp[2 * j2]     = *(const float4*)s;
            xp[2 * j2 + 1] = *(const float4*)(s + 4);
        }
    }

    for (int i = 0; i <= NS; ++i) {
        const bool active = (role == 0) ? (i < NS) : (i >= 1);
        ull lmask = 0;
        unsigned int pk = 0;
        float hn = 0.f;

        if (active) {
            // ---- A: role0 pre-poll x staging (regs -> LDS x-region) ----
            if (role == 0) {
                #pragma unroll
                for (int j2 = 0; j2 < 2; ++j2) {
                    int sid = j2 * 512 + tid;
                    float4 lo = xp[2 * j2], hi = xp[2 * j2 + 1];
                    uint4 val;
                    val.x = pack2bf(lo.x, lo.y);
                    val.y = pack2bf(lo.z, lo.w);
                    val.z = pack2bf(hi.x, hi.y);
                    val.w = pack2bf(hi.z, hi.w);
                    *(uint4*)(smem + sid * 16) = val;
                }
            }

            // ---- B: dual-rail poll (R11 thresholds; local-first on own-role) ----
            if (i > 0) {
                unsigned int thr;
                bool own;
                if (role == 0) {
                    thr = (lane < 32) ? (unsigned int)i
                                      : (unsigned int)(i >= 2 ? i - 2 : 0);
                    own = (lane < 32);
                } else {
                    thr = (unsigned int)i;
                    own = (lane >= 32);
                }
                bool sat = false, lwin = false;
                for (;;) {
                    if (!sat) {
                        if (own) {
                            unsigned int lv = ld_flag_sc0(lfb + lane);
                            if (lv >= thr) { sat = true; lwin = true; }
                            else {
                                unsigned int gv = ld_flag(gfb + lane);
                                if (gv >= thr) sat = true;
                            }
                        } else {
                            unsigned int gv = ld_flag(gfb + lane);
                            if (gv >= thr) sat = true;
                        }
                    }
                    if (__ballot(sat) == 0xFFFFFFFFFFFFFFFFULL) break;
                    __builtin_amdgcn_s_sleep(1);
                }
                lmask = __ballot(lwin);
            }

            const unsigned short* h0prevG = h0g + (((i - 1) & 3) << 15);
            const unsigned short* hpG = (role == 0) ? h0prevG
                                      : h1g + ((i & 1) << 15);
            const unsigned short* hpL = (role == 0) ? h0l + (((i - 1) & 3) << 15)
                                      : h1l + ((i & 1) << 15);

            // ---- C: stage remaining A-parts ----
            if (role == 1) {
                // x-part = h0_{i-1} (GLOBAL rail only — gated by role0 gflags)
                #pragma unroll
                for (int j2 = 0; j2 < 2; ++j2) {
                    int sid = j2 * 512 + tid;
                    int k = (sid >> 6) * 32 + skoff;
                    const ull* p = (const ull*)(h0prevG + (long long)(m0 + srow) * 512 + k);
                    ull lo = ld_h64(p);
                    ull hi = ld_h64(p + 1);
                    uint4 val;
                    val.x = (unsigned int)lo; val.y = (unsigned int)(lo >> 32);
                    val.z = (unsigned int)hi; val.w = (unsigned int)(hi >> 32);
                    *(uint4*)(smem + sid * 16) = val;
                }
            }
            // h-part (both roles): per-slot source select by winning rail
            #pragma unroll
            for (int j2 = 2; j2 < 4; ++j2) {
                int sid = j2 * 512 + tid;
                int k = ((sid >> 6) - 16) * 32 + skoff;
                int pb = (j2 == 2) ? pl1 : pl2;
                if ((lmask >> pb) & 1ull) {
                    u32x4 v = ld16_sc0(hpL + (long long)(m0 + srow) * 512 + k);
                    *(u32x4*)(smem + sid * 16) = v;
                } else {
                    const ull* p = (const ull*)(hpG + (long long)(m0 + srow) * 512 + k);
                    ull lo = ld_h64(p);
                    ull hi = ld_h64(p + 1);
                    uint4 val;
                    val.x = (unsigned int)lo; val.y = (unsigned int)(lo >> 32);
                    val.z = (unsigned int)hi; val.w = (unsigned int)(hi >> 32);
                    *(uint4*)(smem + sid * 16) = val;
                }
            }
            __syncthreads();   // sync1: A staged

            // ---- GEMM: wave (g,kh) -> 16 MFMAs, B from registers ----
            f32x4 acc0 = {0.f,0.f,0.f,0.f}, acc1 = {0.f,0.f,0.f,0.f};
            #pragma unroll
            for (int j = 0; j < 16; j += 2) {
                short8 a0 = *(const short8*)(aBase + (j + 0) * 1024 + lane * 16);
                short8 a1 = *(const short8*)(aBase + (j + 1) * 1024 + lane * 16);
                acc0 = __builtin_amdgcn_mfma_f32_16x16x32_bf16(a0, wreg[j + 0], acc0, 0, 0, 0);
                acc1 = __builtin_amdgcn_mfma_f32_16x16x32_bf16(a1, wreg[j + 1], acc1, 0, 0, 0);
            }
            f32x4 accS = acc0 + acc1;
            {
                int u_g  = lane & 15;
                int mrow = (lane >> 4) * 4;
                #pragma unroll
                for (int r = 0; r < 4; ++r)
                    Gp[w][mrow + r][u_g] = accS[r];
            }
            __syncthreads();   // sync2: Gp ready

            // ---- fused LSTM cell (tid<256): LOCAL store only (fast rail) ----
            if (tid < 256) {
                float s0 = Gp[0][m_l][u_l] + Gp[4][m_l][u_l] + bias_i;
                float s1 = Gp[1][m_l][u_l] + Gp[5][m_l][u_l] + bias_f;
                float s2 = Gp[2][m_l][u_l] + Gp[6][m_l][u_l] + bias_g;
                float s3 = Gp[3][m_l][u_l] + Gp[7][m_l][u_l] + bias_o;
                float ii = 1.f / (1.f + expf(-s0));
                float ff = 1.f / (1.f + expf(-s1));
                float gv = tanhf(s2);
                float oo = 1.f / (1.f + expf(-s3));
                cReg = ff * cReg + ii * gv;
                hn = oo * tanhf(cReg);

                float hn_p = __shfl_xor(hn, 1);
                pk = pack2bf(hn, hn_p);
                if ((u_l & 1) == 0) {
                    unsigned short* lbuf = (role == 0)
                        ? h0l + ((i & 3) << 15)
                        : h1l + (((i - 1) & 1) << 15);
                    *(volatile unsigned int*)((unsigned int*)lbuf
                        + ((bcell * NH + ucell) >> 1)) = pk;
                }
                // last iter (role1, i==NS): D is skipped — store out/tail here
                if (role == 1 && i == NS) {
                    int s = i - 1;
                    out[(long long)bcell * (NS * NH) + (long long)s * NH + ucell] = hn;
                    float* dst = out + (long long)NB * NS * NH;
                    dst[bcell * NH + ucell] = hn;
                    dst[NB * NH + bcell * NH + ucell] = cReg;
                }
            }
        }

        // ---- D: split drain — local flag fast, then global mirror + flag ----
        if (i < NS) {
            __syncthreads();   // sync3a: local (plain) stores drained
            if (tid == 0) *(volatile unsigned int*)mylf = (unsigned int)(i + 1);

            if (active && tid < 256) {
                if ((u_l & 1) == 0) {
                    unsigned short* gbuf = (role == 0)
                        ? h0g + ((i & 3) << 15)
                        : h1g + (((i - 1) & 1) << 15);
                    st_h32((unsigned int*)gbuf + ((bcell * NH + ucell) >> 1), pk);
                }
                if (role == 1) {
                    int s = i - 1;
                    out[(long long)bcell * (NS * NH) + (long long)s * NH + ucell] = hn;
                }
            }
            __syncthreads();   // sync3b: sc1 mirror + out drained
            if (tid == 0) st_flag(mygf, (unsigned int)(i + 1));

            if (role == 0 && i + 1 < NS) {
                #pragma unroll
                for (int j2 = 0; j2 < 2; ++j2) {
                    int sid = j2 * 512 + tid;
                    int k = (sid >> 6) * 32 + skoff;
                    const float* s = input + (long long)(m0 + srow) * (NS * ND)
                                           + (long long)(i + 1) * ND + k;
                    xp[2 * j2]     = *(const float4*)s;
                    xp[2 * j2 + 1] = *(const float4*)(s + 4);
                }
            }
        }
    }
}

extern "C" void kernel_launch(void* const* d_in, const int* in_sizes, int n_in,
                              void* d_out, int out_size, void* d_ws, size_t ws_size,
                              hipStream_t stream) {
    const float* input = (const float*)d_in[0];
    const float* enc_h = (const float*)d_in[1];
    const float* enc_c = (const float*)d_in[2];
    const float* W_ih  = (const float*)d_in[3];
    const float* W_hh  = (const float*)d_in[4];
    const float* b_ih  = (const float*)d_in[5];
    const float* b_hh  = (const float*)d_in[6];
    float* out = (float*)d_out;
    unsigned char* ws = (unsigned char*)d_ws;

    unsigned short* wpk = (unsigned short*)(ws + WPK_OFF);
    unsigned short* h0g = (unsigned short*)(ws + H0G_OFF);
    unsigned short* h1g = (unsigned short*)(ws + H1G_OFF);
    unsigned short* h0l = (unsigned short*)(ws + H0L_OFF);
    unsigned short* h1l = (unsigned short*)(ws + H1L_OFF);
    unsigned int*   gfl = (unsigned int*)(ws + GFL_OFF);
    unsigned int*   lfl = (unsigned int*)(ws + LFL_OFF);

    prep_weights_k<<<2048, 256, 0, stream>>>(W_ih, W_hh, (unsigned int*)wpk);
    prep_state_k<<<128, 256, 0, stream>>>(enc_h, h0g, h1g, h0l, h1l, gfl, lfl);
    lstm_persist_k<<<256, 512, 0, stream>>>(input, enc_c, b_ih, b_hh, wpk,
                                            h0g, h1g, h0l, h1l, out, gfl, lfl);
}